// Round 1
// 141.855 us; speedup vs baseline: 1.0234x; 1.0234x over previous
//
#include <hip/hip_runtime.h>

// ConvT3d(32->16,k3,s2,p1)+BN+4^3 avgpool, bf16 MFMA, 4096-block grid.
// R6: occupancy push. Combined VGPR+AGPR was ~132 (68 arch + 64 acc) -> 2
// waves/SIMD. kh-outer B-phasing keeps only 3 B-frags (12 VGPR) live instead
// of 9 (36), __launch_bounds__(256,4) caps the unified file at 128 -> 4
// waves/SIMD. v_cvt_pk_bf16_f32 replaces manual RNE pack (same rounding).
// x-halo LDS layout [dihi][g][iw][o] (g=ci>>3,o=ci&7) unchanged.
// Parity decomposition (validated R1-R5): even o: k=1,i=o/2;
//   odd o=2m+1: k=0 -> i=m+1 ; k=2 -> i=m.
// (hi,kh,oh) pairs regrouped by kh (same 6 pairs as the R5 HN/HKH/HOH tables):
//   kh0: (hi1,oh1),(hi2,oh3); kh1: (hi0,oh0),(hi1,oh2); kh2: (hi0,oh1),(hi1,oh3)

typedef __attribute__((ext_vector_type(8))) short bf16x8;
typedef __attribute__((ext_vector_type(4))) float f32x4;

static __device__ __forceinline__ unsigned short f2bf(float f) {
    unsigned int u = __float_as_uint(f);
    u = (u + 0x7fffu + ((u >> 16) & 1u)) >> 16;   // RNE
    return (unsigned short)u;
}
// RNE pack of 2 f32 -> 2 bf16 in one instr (identical rounding to f2bf)
static __device__ __forceinline__ unsigned cvtpk(float a, float b) {
    unsigned r;
    asm("v_cvt_pk_bf16_f32 %0, %1, %2" : "=v"(r) : "v"(a), "v"(b));
    return r;
}

// ---- w convert: w[ci][co][tap] fp32 -> wT[tap][co][ci] bf16 (tap=kd*9+kh*3+kw)
__global__ __launch_bounds__(256)
void kw(const float* __restrict__ w, unsigned short* __restrict__ wT)
{
    const int idx = blockIdx.x * 256 + threadIdx.x;
    if (idx < 13824) {
        const int ci = idx & 31, co = (idx >> 5) & 15, tap = idx >> 9;
        wT[idx] = f2bf(w[(ci * 16 + co) * 27 + tap]);
    }
}

// ---- fused stage + convT + BN-stats + pool partials
__global__ __launch_bounds__(256, 4)
void convf2(const float* __restrict__ x,
            const unsigned short* __restrict__ wT,
            const float* __restrict__ bias,
            float* __restrict__ pooled,
            float* __restrict__ psum, float* __restrict__ psq)
{
    const int ht = blockIdx.x, dt = blockIdx.y, n = blockIdx.z;
    const int tid = threadIdx.x;
    const int v = tid >> 6, lane = tid & 63;
    const int t = v & 1, odp = v >> 1;          // ow 16-tile, od pair
    const int c = lane & 15, qd = lane >> 4;    // co / A-row m, K-granule

    // xs[dihi(9)][g(4)][iw(33)][o(8)] bf16 -> 9*1056 shorts = 19008 B
    __shared__ unsigned short xs[9504];
    __shared__ float sred[4][16], qred[4][16], pbuf[2][8][16];

    // ---- stage x: thread = (plane-half, g, iw); 8 ci-strided b32 loads,
    // pack -> one ds_write_b128. 5 passes cover 9 planes + zero column.
    #pragma unroll
    for (int p = 0; p < 5; ++p) {
        const int dihi = p * 2 + (tid >> 7);
        if (dihi < 9) {
            const int iw = tid & 31, g = (tid >> 5) & 3;
            const int di = dihi / 3, hi = dihi - di * 3;
            const int id = 2*dt + di, ih = 2*ht + hi;
            const bool ok = (id < 32) && (ih < 32);
            const float* px = x + ((((n*32 + g*8)*32 + id)*32 + ih)*32) + iw;
            float f[8];
            #pragma unroll
            for (int j = 0; j < 8; ++j)
                f[j] = ok ? px[j * 32768] : 0.f;
            uint4 u;
            u.x = cvtpk(f[0], f[1]); u.y = cvtpk(f[2], f[3]);
            u.z = cvtpk(f[4], f[5]); u.w = cvtpk(f[6], f[7]);
            *(uint4*)(xs + dihi*1056 + g*264 + iw*8) = u;
        }
    }
    if (tid < 36) {
        const int dihi = tid >> 2, g = tid & 3;
        *(uint4*)(xs + dihi*1056 + g*264 + 256) = make_uint4(0,0,0,0);
    }

    __syncthreads();

    f32x4 acc[2][4][2];   // [ol][oh][par]
    #pragma unroll
    for (int ol = 0; ol < 2; ++ol)
        #pragma unroll
        for (int oh = 0; oh < 4; ++oh)
            #pragma unroll
            for (int par = 0; par < 2; ++par)
                acc[ol][oh][par] = (f32x4){0.f,0.f,0.f,0.f};

    const int iwb = 16 * t + c;
    auto LDA = [&](int dihi, int sofs) -> bf16x8 {
        return *(const bf16x8*)(xs + dihi*1056 + qd*264 + (iwb + sofs)*8);
    };
    auto LDB = [&](int tap) -> bf16x8 {
        return *(const bf16x8*)(wT + tap * 512 + c * 32 + qd * 8);
    };

    // kh-outer pair table: [kh][pair] -> (hi, oh). Only 3 B-frags live.
    constexpr int KHP[3][2][2] = {
        {{1,1},{2,3}},   // kh0
        {{0,0},{1,2}},   // kh1
        {{0,1},{1,3}},   // kh2
    };

    auto PH = [&](int ol, int base, int di) {
        #pragma unroll
        for (int kh = 0; kh < 3; ++kh) {
            const bf16x8 B0 = LDB(base + kh*3 + 0);
            const bf16x8 B1 = LDB(base + kh*3 + 1);
            const bf16x8 B2 = LDB(base + kh*3 + 2);
            #pragma unroll
            for (int p = 0; p < 2; ++p) {
                const int hi = KHP[kh][p][0], oh = KHP[kh][p][1];
                const bf16x8 A0 = LDA(di*3 + hi, 0), A1 = LDA(di*3 + hi, 1);
                acc[ol][oh][0] = __builtin_amdgcn_mfma_f32_16x16x32_bf16(
                    A0, B1, acc[ol][oh][0], 0, 0, 0);
                acc[ol][oh][1] = __builtin_amdgcn_mfma_f32_16x16x32_bf16(
                    A1, B0, acc[ol][oh][1], 0, 0, 0);
                acc[ol][oh][1] = __builtin_amdgcn_mfma_f32_16x16x32_bf16(
                    A0, B2, acc[ol][oh][1], 0, 0, 0);
            }
        }
    };

    PH(0,  9, odp);       // kd=1 -> ol0
    PH(1, 18, odp);       // kd=2 -> ol1
    PH(1,  0, odp + 1);   // kd=0 -> ol1

    // ---- epilogue: bias, BN stats (masked), pool partials (validated R2-R5)
    const float bv = bias[c];
    float s = 0.f, sq = 0.f;
    float P[2] = {0.f, 0.f};
    #pragma unroll
    for (int ol = 0; ol < 2; ++ol) {
        const int odg = 2*odp + ol;
        const bool odok = !(dt == 15 && odg == 3);
        #pragma unroll
        for (int oh = 0; oh < 4; ++oh) {
            const bool ohok = !(ht == 15 && oh == 3);
            #pragma unroll
            for (int par = 0; par < 2; ++par)
                #pragma unroll
                for (int r = 0; r < 4; ++r) {
                    const float val = acc[ol][oh][par][r] + bv;
                    const bool owok = !(par == 1 && t == 1 && qd == 3 && r == 3);
                    const float mk = (odok && ohok && owok) ? 1.f : 0.f;
                    s += mk * val; sq += mk * val * val;
                    P[r >> 1] += val;
                }
        }
    }
    s  += __shfl_xor(s, 16, 64);  s  += __shfl_xor(s, 32, 64);
    sq += __shfl_xor(sq, 16, 64); sq += __shfl_xor(sq, 32, 64);

    if (lane < 16) { sred[v][lane] = s; qred[v][lane] = sq; }
    if (odp == 0 && dt < 15 && ht < 15) {
        pbuf[t][2*qd + 0][c] = P[0];
        pbuf[t][2*qd + 1][c] = P[1];
    }
    __syncthreads();
    if (tid < 16) {
        const int blk = (n*16 + dt)*16 + ht;
        psum[tid*4096 + blk] = sred[0][tid]+sred[1][tid]+sred[2][tid]+sred[3][tid];
        psq [tid*4096 + blk] = qred[0][tid]+qred[1][tid]+qred[2][tid]+qred[3][tid];
    }
    if (odp == 1 && dt < 15 && ht < 15) {
        #pragma unroll
        for (int jj = 0; jj < 2; ++jj) {
            const int jl = 2*qd + jj, jg = 8*t + jl;
            if (jg < 15) {
                const float tot = pbuf[t][jl][c] + P[jj];
                pooled[(n*16 + c)*3375 + dt*225 + ht*15 + jg] = tot * (1.f/64.f);
            }
        }
    }
}

__global__ void bnfinal(const float* __restrict__ psum, const float* __restrict__ psq,
                        const float* __restrict__ gamma, const float* __restrict__ beta,
                        float* __restrict__ bn)
{
    const int co = blockIdx.x;
    const int t  = threadIdx.x;
    float S = 0, Q = 0;
    for (int blk = t; blk < 4096; blk += 256) {
        S += psum[co*4096 + blk];
        Q += psq [co*4096 + blk];
    }
    #pragma unroll
    for (int off = 32; off > 0; off >>= 1) {
        S += __shfl_down(S, off, 64);
        Q += __shfl_down(Q, off, 64);
    }
    __shared__ float rs[4], rq[4];
    if ((t & 63) == 0) { rs[t >> 6] = S; rq[t >> 6] = Q; }
    __syncthreads();
    if (t == 0) {
        S = rs[0] + rs[1] + rs[2] + rs[3];
        Q = rq[0] + rq[1] + rq[2] + rq[3];
        const float cnt = 16.f * 63.f * 63.f * 63.f;
        const float mean = S / cnt;
        const float var  = Q / cnt - mean * mean;
        const float inv  = rsqrtf(var + 1e-5f);
        const float sc   = inv * gamma[co];
        bn[co]      = sc;
        bn[16 + co] = beta[co] - mean * sc;
    }
}

__global__ void finalize(const float* __restrict__ pooled, const float* __restrict__ bn,
                         float* __restrict__ out)
{
    const int i  = blockIdx.x * 256 + threadIdx.x;   // 864000 = 3375*256
    const int co = (i / 3375) & 15;
    out[i] = pooled[i] * bn[co] + bn[16 + co];
}

extern "C" void kernel_launch(void* const* d_in, const int* in_sizes, int n_in,
                              void* d_out, int out_size, void* d_ws, size_t ws_size,
                              hipStream_t stream)
{
    const float* x     = (const float*)d_in[0];
    const float* w     = (const float*)d_in[1];
    const float* b     = (const float*)d_in[2];
    const float* gamma = (const float*)d_in[3];
    const float* beta  = (const float*)d_in[4];
    float* out = (float*)d_out;

    char* wsb = (char*)d_ws;
    unsigned short* wT = (unsigned short*)wsb;        // 27,648 B
    float* pooled = (float*)(wsb + 27648);            // 3,456,000 B
    float* psum   = (float*)(wsb + 27648 + 3456000);  // 262,144 B
    float* psq    = (float*)(wsb + 27648 + 3456000 + 262144);
    float* bn     = (float*)(wsb + 27648 + 3456000 + 2*262144);

    kw<<<54, 256, 0, stream>>>(w, wT);
    dim3 grid(16, 16, 16);   // (ht, dt, n)
    convf2<<<grid, 256, 0, stream>>>(x, wT, b, pooled, psum, psq);
    bnfinal<<<16, 256, 0, stream>>>(psum, psq, gamma, beta, bn);
    finalize<<<3375, 256, 0, stream>>>(pooled, bn, out);
}